// Round 1
// baseline (1395.258 us; speedup 1.0000x reference)
//
#include <hip/hip_runtime.h>
#include <math.h>

// ---------------- problem constants ----------------
constexpr int NN   = 20000;          // nodes
constexpr int NE   = 320000;         // edges
constexpr int ND   = 64;             // node dim
constexpr int ED   = 16;             // edge dim
constexpr int HID  = 256;
constexpr int HEADS= 8;
constexpr int CH   = 32;             // channels per head
constexpr int NB   = 16;             // graphs
constexpr int NL   = 3;              // layers
constexpr float NEG_SLOPE = 0.2f;
constexpr int EN   = NE + NN;        // edges incl self-loops

// ---------------- workspace layout (float units) ----------------
constexpr size_t OFF_H      = 0;
constexpr size_t OFF_XL     = OFF_H      + (size_t)NN*HID;     // 5.12M
constexpr size_t OFF_XR     = OFF_XL     + (size_t)NN*HID;
constexpr size_t OFF_EA     = OFF_XR     + (size_t)NN*HID;
constexpr size_t OFF_LOOPEA = OFF_EA     + (size_t)NE*ED;
constexpr size_t OFF_LOGITS = OFF_LOOPEA + (size_t)NN*ED;
constexpr size_t OFF_HG     = OFF_LOGITS + (size_t)EN*HEADS;
constexpr size_t OFF_INT    = OFF_HG     + (size_t)NB*HID;
// int region (indexed in ints from OFF_INT)
constexpr size_t IOFF_DEG    = 0;
constexpr size_t IOFF_ROWOFF = IOFF_DEG    + NN;
constexpr size_t IOFF_CURSOR = IOFF_ROWOFF + NN + 1;
constexpr size_t IOFF_CSRSRC = IOFF_CURSOR + NN;
constexpr size_t IOFF_CSREID = IOFF_CSRSRC + NE;
constexpr size_t IOFF_CNT    = IOFF_CSREID + NE;

// ---------------- utility ----------------
__global__ __launch_bounds__(256) void k_zero(float* p, int n) {
  int i = blockIdx.x*256 + threadIdx.x;
  for (; i < n; i += gridDim.x*256) p[i] = 0.f;
}

// h = x @ node_W + node_b   (x: [NN,64], W: [64,256])
__global__ __launch_bounds__(256) void k_node_embed(const float* __restrict__ x,
    const float* __restrict__ W, const float* __restrict__ b, float* __restrict__ h) {
  __shared__ float xs[4][ND];
  int n0 = blockIdx.x * 4;
  int tid = threadIdx.x;
  { int r = tid >> 6, j = tid & 63; xs[r][j] = x[(size_t)(n0+r)*ND + j]; }
  __syncthreads();
  int c = tid;
  float a0 = b[c], a1 = b[c], a2 = b[c], a3 = b[c];
  #pragma unroll 8
  for (int j = 0; j < ND; ++j) {
    float w = W[(size_t)j*HID + c];
    a0 += xs[0][j]*w; a1 += xs[1][j]*w; a2 += xs[2][j]*w; a3 += xs[3][j]*w;
  }
  h[(size_t)(n0+0)*HID+c]=a0; h[(size_t)(n0+1)*HID+c]=a1;
  h[(size_t)(n0+2)*HID+c]=a2; h[(size_t)(n0+3)*HID+c]=a3;
}

// ea = edge_attr @ edge_W + edge_b  (attr:[NE,16], W:[16,16])
__global__ __launch_bounds__(256) void k_edge_embed(const float* __restrict__ attr,
    const float* __restrict__ W, const float* __restrict__ b, float* __restrict__ ea) {
  int i = blockIdx.x*256 + threadIdx.x;
  const int total = NE * ED;
  for (; i < total; i += gridDim.x*256) {
    int e = i >> 4, c = i & 15;
    const float* row = attr + (size_t)e*ED;
    float acc = b[c];
    #pragma unroll
    for (int j = 0; j < ED; ++j) acc += row[j] * W[j*ED + c];
    ea[i] = acc;
  }
}

__global__ __launch_bounds__(256) void k_deg(const int* __restrict__ dst, int* deg) {
  int i = blockIdx.x*256 + threadIdx.x;
  for (; i < NE; i += gridDim.x*256) atomicAdd(&deg[dst[i]], 1);
}

__global__ __launch_bounds__(256) void k_cnt(const int* __restrict__ batch, int* cnt) {
  int i = blockIdx.x*256 + threadIdx.x;
  for (; i < NN; i += gridDim.x*256) atomicAdd(&cnt[batch[i]], 1);
}

// single-block scan of deg -> row_off (excl prefix) + cursor copy; row_off[NN]=E
__global__ __launch_bounds__(1024) void k_scan(const int* __restrict__ deg,
    int* __restrict__ row_off, int* __restrict__ cursor) {
  __shared__ int sm[1024];
  const int CHK = (NN + 1023) / 1024;   // 20
  int t = threadIdx.x;
  int base = t * CHK;
  int s = 0;
  for (int i = 0; i < CHK; ++i) { int idx = base+i; if (idx < NN) s += deg[idx]; }
  sm[t] = s; __syncthreads();
  for (int off = 1; off < 1024; off <<= 1) {
    int v = (t >= off) ? sm[t-off] : 0;
    __syncthreads();
    sm[t] += v;
    __syncthreads();
  }
  int run = (t == 0) ? 0 : sm[t-1];
  for (int i = 0; i < CHK; ++i) {
    int idx = base+i;
    if (idx < NN) { row_off[idx] = run; cursor[idx] = run; run += deg[idx]; }
  }
  if (t == 1023) row_off[NN] = sm[1023];
}

__global__ __launch_bounds__(256) void k_fill(const int* __restrict__ src, const int* __restrict__ dst,
    int* cursor, int* __restrict__ csr_src, int* __restrict__ csr_eid) {
  int e = blockIdx.x*256 + threadIdx.x;
  for (; e < NE; e += gridDim.x*256) {
    int pos = atomicAdd(&cursor[dst[e]], 1);
    csr_src[pos] = src[e];
    csr_eid[pos] = e;
  }
}

// loop_ea[n,c] = sum_{e: dst=n} ea[e,c] / max(deg,1)
__global__ __launch_bounds__(256) void k_loopea(const float* __restrict__ ea,
    const int* __restrict__ row_off, const int* __restrict__ csr_eid, float* __restrict__ loopea) {
  int i = blockIdx.x*256 + threadIdx.x;
  const int total = NN * ED;
  for (; i < total; i += gridDim.x*256) {
    int n = i >> 4, c = i & 15;
    int b0 = row_off[n], b1 = row_off[n+1];
    float s = 0.f;
    for (int k = b0; k < b1; ++k) s += ea[(size_t)csr_eid[k]*ED + c];
    int dg = b1 - b0;
    loopea[i] = s / (float)(dg > 1 ? dg : 1);
  }
}

// dual GEMM: C{0,1} = A @ B{0,1} + bias{0,1};  A:[M,256] B:[256,256]
constexpr int BM = 64, BN = 64, BK = 32;
__global__ __launch_bounds__(256) void k_gemm_dual(const float* __restrict__ A,
    const float* __restrict__ B0, const float* __restrict__ B1,
    const float* __restrict__ bias0, const float* __restrict__ bias1,
    float* __restrict__ C0, float* __restrict__ C1, int M) {
  __shared__ float As[BK][BM+4];   // transposed A tile, +4 pad keeps 16B align & banks spread
  __shared__ float Bs[BK][BN];
  const float* B    = blockIdx.z ? B1 : B0;
  const float* bias = blockIdx.z ? bias1 : bias0;
  float* C          = blockIdx.z ? C1 : C0;
  int tid = threadIdx.x;
  int tx = tid & 15, ty = tid >> 4;          // 16x16 threads, 4x4 micro-tile
  int m0 = blockIdx.x * BM, n0 = blockIdx.y * BN;
  float acc[4][4] = {};
  for (int k0 = 0; k0 < HID; k0 += BK) {
    for (int i = tid; i < BM*(BK/4); i += 256) {       // 512 float4
      int m = i >> 3, k4 = (i & 7) << 2;
      float4 v = make_float4(0.f,0.f,0.f,0.f);
      int gm = m0 + m;
      if (gm < M) v = *(const float4*)(A + (size_t)gm*HID + k0 + k4);
      As[k4+0][m]=v.x; As[k4+1][m]=v.y; As[k4+2][m]=v.z; As[k4+3][m]=v.w;
    }
    for (int i = tid; i < BK*(BN/4); i += 256) {       // 512 float4
      int kk = i >> 4, n4 = (i & 15) << 2;
      *(float4*)&Bs[kk][n4] = *(const float4*)(B + (size_t)(k0+kk)*HID + n0 + n4);
    }
    __syncthreads();
    #pragma unroll
    for (int kk = 0; kk < BK; ++kk) {
      float4 a4 = *(const float4*)&As[kk][ty*4];
      float4 b4 = *(const float4*)&Bs[kk][tx*4];
      float av[4] = {a4.x,a4.y,a4.z,a4.w};
      float bv[4] = {b4.x,b4.y,b4.z,b4.w};
      #pragma unroll
      for (int r = 0; r < 4; ++r)
        #pragma unroll
        for (int cc = 0; cc < 4; ++cc)
          acc[r][cc] += av[r]*bv[cc];
    }
    __syncthreads();
  }
  float4 bb = *(const float4*)(bias + n0 + tx*4);
  #pragma unroll
  for (int r = 0; r < 4; ++r) {
    int gm = m0 + ty*4 + r;
    if (gm < M) {
      float4 o = make_float4(acc[r][0]+bb.x, acc[r][1]+bb.y, acc[r][2]+bb.z, acc[r][3]+bb.w);
      *(float4*)(C + (size_t)gm*HID + n0 + tx*4) = o;
    }
  }
}

// per-edge (incl self-loops) attention logits; one wave per edge
__global__ __launch_bounds__(256) void k_edge_logits(const float* __restrict__ xl,
    const float* __restrict__ xr, const float* __restrict__ ea, const float* __restrict__ loopea,
    const int* __restrict__ src, const int* __restrict__ dst,
    const float* __restrict__ We, const float* __restrict__ att, float* __restrict__ logits) {
  int lane = threadIdx.x & 63;
  int wid  = (blockIdx.x*256 + threadIdx.x) >> 6;
  int nw   = gridDim.x * 4;
  int c4   = lane * 4;
  int hh   = lane >> 3;
  float4 wv[16];
  #pragma unroll
  for (int j = 0; j < 16; ++j) wv[j] = *(const float4*)(We + (size_t)j*HID + c4);
  float at0 = att[hh*CH + (lane&7)*4 + 0];
  float at1 = att[hh*CH + (lane&7)*4 + 1];
  float at2 = att[hh*CH + (lane&7)*4 + 2];
  float at3 = att[hh*CH + (lane&7)*4 + 3];
  for (int e = wid; e < EN; e += nw) {
    int s, d; const float* eap;
    if (e < NE) { s = src[e]; d = dst[e]; eap = ea + (size_t)e*ED; }
    else        { s = e - NE; d = s;      eap = loopea + (size_t)s*ED; }
    float eav = (lane < 16) ? eap[lane] : 0.f;
    float4 acc = make_float4(0.f,0.f,0.f,0.f);
    #pragma unroll
    for (int j = 0; j < 16; ++j) {
      float ej = __shfl(eav, j);
      acc.x += ej*wv[j].x; acc.y += ej*wv[j].y; acc.z += ej*wv[j].z; acc.w += ej*wv[j].w;
    }
    float4 l4 = *(const float4*)(xl + (size_t)s*HID + c4);
    float4 r4 = *(const float4*)(xr + (size_t)d*HID + c4);
    float z0 = l4.x + r4.x + acc.x;
    float z1 = l4.y + r4.y + acc.y;
    float z2 = l4.z + r4.z + acc.z;
    float z3 = l4.w + r4.w + acc.w;
    z0 = z0 > 0.f ? z0 : z0*NEG_SLOPE;
    z1 = z1 > 0.f ? z1 : z1*NEG_SLOPE;
    z2 = z2 > 0.f ? z2 : z2*NEG_SLOPE;
    z3 = z3 > 0.f ? z3 : z3*NEG_SLOPE;
    float p = at0*z0 + at1*z1 + at2*z2 + at3*z3;
    p += __shfl_xor(p, 1);
    p += __shfl_xor(p, 2);
    p += __shfl_xor(p, 4);
    if ((lane & 7) == 0) logits[(size_t)e*HEADS + hh] = p;
  }
}

// per-node segment softmax + alpha-weighted aggregation + residual + bias; one wave per node
__global__ __launch_bounds__(256) void k_node_agg(const float* __restrict__ xl,
    const float* __restrict__ logits, const int* __restrict__ row_off,
    const int* __restrict__ csr_src, const int* __restrict__ csr_eid,
    const float* __restrict__ bias, float* __restrict__ h) {
  int lane = threadIdx.x & 63;
  int wid  = (blockIdx.x*256 + threadIdx.x) >> 6;
  int nw   = gridDim.x * 4;
  int c4   = lane * 4;
  int hh   = lane >> 3;
  for (int n = wid; n < NN; n += nw) {
    int b0 = row_off[n], b1 = row_off[n+1];
    float selfl = logits[(size_t)(NE+n)*HEADS + hh];
    float m = selfl;
    for (int k = b0; k < b1; ++k) m = fmaxf(m, logits[(size_t)csr_eid[k]*HEADS + hh]);
    float denom = __expf(0.f); // placeholder avoided: use expf below
    denom = expf(selfl - m);
    for (int k = b0; k < b1; ++k) denom += expf(logits[(size_t)csr_eid[k]*HEADS + hh] - m);
    float inv = 1.f / denom;
    float4 acc;
    {
      float w = expf(selfl - m) * inv;
      float4 v = *(const float4*)(xl + (size_t)n*HID + c4);
      acc = make_float4(w*v.x, w*v.y, w*v.z, w*v.w);
    }
    for (int k = b0; k < b1; ++k) {
      float w = expf(logits[(size_t)csr_eid[k]*HEADS + hh] - m) * inv;
      float4 v = *(const float4*)(xl + (size_t)csr_src[k]*HID + c4);
      acc.x += w*v.x; acc.y += w*v.y; acc.z += w*v.z; acc.w += w*v.w;
    }
    float4 hv = *(const float4*)(h + (size_t)n*HID + c4);
    float4 b4 = *(const float4*)(bias + c4);
    float4 o = make_float4(hv.x+acc.x+b4.x, hv.y+acc.y+b4.y, hv.z+acc.z+b4.z, hv.w+acc.w+b4.w);
    *(float4*)(h + (size_t)n*HID + c4) = o;
  }
}

// mean-pool numerator: run-accumulated atomics (batch is sorted)
__global__ __launch_bounds__(256) void k_pool(const float* __restrict__ h,
    const int* __restrict__ batch, float* __restrict__ hg) {
  int c = threadIdx.x;
  int per = (NN + gridDim.x - 1) / gridDim.x;
  int n0 = blockIdx.x * per, n1 = min(NN, n0 + per);
  if (n0 >= n1) return;
  int cur = batch[n0];
  float acc = 0.f;
  for (int n = n0; n < n1; ++n) {
    int b = batch[n];
    if (b != cur) { atomicAdd(&hg[(size_t)cur*HID + c], acc); acc = 0.f; cur = b; }
    acc += h[(size_t)n*HID + c];
  }
  atomicAdd(&hg[(size_t)cur*HID + c], acc);
}

// out = gelu(hg/cnt @ W1 + b1) @ W2 + b2 ; one block per graph
__global__ __launch_bounds__(256) void k_mlp(const float* __restrict__ hg, const int* __restrict__ cnt,
    const float* __restrict__ W1, const float* __restrict__ b1,
    const float* __restrict__ W2, const float* __restrict__ b2, float* __restrict__ out) {
  __shared__ float row[HID];
  __shared__ float zrow[HID];
  int b = blockIdx.x, c = threadIdx.x;
  float cn = (float)cnt[b]; cn = cn < 1.f ? 1.f : cn;
  row[c] = hg[(size_t)b*HID + c] / cn;
  __syncthreads();
  float acc = b1[c];
  for (int j = 0; j < HID; ++j) acc += row[j] * W1[(size_t)j*HID + c];
  float g = 0.5f * acc * (1.f + erff(acc * 0.70710678118654752440f));
  zrow[c] = g;
  __syncthreads();
  float acc2 = b2[c];
  for (int j = 0; j < HID; ++j) acc2 += zrow[j] * W2[(size_t)j*HID + c];
  out[(size_t)b*HID + c] = acc2;
}

extern "C" void kernel_launch(void* const* d_in, const int* in_sizes, int n_in,
                              void* d_out, int out_size, void* d_ws, size_t ws_size,
                              hipStream_t stream) {
  const float* x         = (const float*)d_in[0];
  const int*   edge_index= (const int*)  d_in[1];
  const float* edge_attr = (const float*)d_in[2];
  const int*   batch     = (const int*)  d_in[3];
  const float* node_W    = (const float*)d_in[4];
  const float* node_b    = (const float*)d_in[5];
  const float* edge_W    = (const float*)d_in[6];
  const float* edge_b    = (const float*)d_in[7];
  const float* Wl        = (const float*)d_in[8];
  const float* bl        = (const float*)d_in[9];
  const float* Wr        = (const float*)d_in[10];
  const float* br        = (const float*)d_in[11];
  const float* We        = (const float*)d_in[12];
  const float* att       = (const float*)d_in[13];
  const float* conv_bias = (const float*)d_in[14];
  const float* W1        = (const float*)d_in[15];
  const float* b1        = (const float*)d_in[16];
  const float* W2        = (const float*)d_in[17];
  const float* b2        = (const float*)d_in[18];
  const int* srcp = edge_index;
  const int* dstp = edge_index + NE;

  float* ws = (float*)d_ws;
  float* h      = ws + OFF_H;
  float* xl     = ws + OFF_XL;
  float* xr     = ws + OFF_XR;
  float* ea     = ws + OFF_EA;
  float* loopea = ws + OFF_LOOPEA;
  float* logits = ws + OFF_LOGITS;
  float* hg     = ws + OFF_HG;
  int* ib       = (int*)(ws + OFF_INT);
  int* deg      = ib + IOFF_DEG;
  int* row_off  = ib + IOFF_ROWOFF;
  int* cursor   = ib + IOFF_CURSOR;
  int* csr_src  = ib + IOFF_CSRSRC;
  int* csr_eid  = ib + IOFF_CSREID;
  int* cnt      = ib + IOFF_CNT;

  // zero accumulators (must happen every launch; harness doesn't re-poison)
  k_zero<<<8, 256, 0, stream>>>(hg, NB*HID);
  k_zero<<<80, 256, 0, stream>>>((float*)deg, NN);
  k_zero<<<1, 256, 0, stream>>>((float*)cnt, NB);

  k_node_embed<<<NN/4, 256, 0, stream>>>(x, node_W, node_b, h);
  k_edge_embed<<<2048, 256, 0, stream>>>(edge_attr, edge_W, edge_b, ea);
  k_deg<<<1250, 256, 0, stream>>>(dstp, deg);
  k_cnt<<<80, 256, 0, stream>>>(batch, cnt);
  k_scan<<<1, 1024, 0, stream>>>(deg, row_off, cursor);
  k_fill<<<1250, 256, 0, stream>>>(srcp, dstp, cursor, csr_src, csr_eid);
  k_loopea<<<1250, 256, 0, stream>>>(ea, row_off, csr_eid, loopea);

  for (int l = 0; l < NL; ++l) {
    dim3 g((NN + BM - 1)/BM, HID/BN, 2);
    k_gemm_dual<<<g, 256, 0, stream>>>(h,
        Wl + (size_t)l*HID*HID, Wr + (size_t)l*HID*HID,
        bl + (size_t)l*HID,     br + (size_t)l*HID,
        xl, xr, NN);
    k_edge_logits<<<2560, 256, 0, stream>>>(xl, xr, ea, loopea, srcp, dstp,
        We + (size_t)l*ED*HID, att + (size_t)l*HEADS*CH, logits);
    k_node_agg<<<1280, 256, 0, stream>>>(xl, logits, row_off, csr_src, csr_eid,
        conv_bias + (size_t)l*HID, h);
  }

  k_pool<<<80, 256, 0, stream>>>(h, batch, hg);
  k_mlp<<<NB, 256, 0, stream>>>(hg, cnt, W1, b1, W2, b2, (float*)d_out);
}

// Round 2
// 1196.492 us; speedup vs baseline: 1.1661x; 1.1661x over previous
//
#include <hip/hip_runtime.h>
#include <math.h>

// ---------------- problem constants ----------------
constexpr int NN   = 20000;          // nodes
constexpr int NE   = 320000;         // edges
constexpr int ND   = 64;             // node dim
constexpr int ED   = 16;             // edge dim
constexpr int HID  = 256;
constexpr int HEADS= 8;
constexpr int CH   = 32;             // channels per head
constexpr int NB   = 16;             // graphs
constexpr int NL   = 3;              // layers
constexpr float NEG_SLOPE = 0.2f;
constexpr int EN   = NE + NN;        // edges incl self-loops

// ---------------- workspace layout (float units) ----------------
constexpr size_t OFF_H      = 0;
constexpr size_t OFF_XL     = OFF_H      + (size_t)NN*HID;
constexpr size_t OFF_XR     = OFF_XL     + (size_t)NN*HID;
constexpr size_t OFF_EA     = OFF_XR     + (size_t)NN*HID;
constexpr size_t OFF_LOOPEA = OFF_EA     + (size_t)NE*ED;
constexpr size_t OFF_LOGITS = OFF_LOOPEA + (size_t)NN*ED;
constexpr size_t OFF_HG     = OFF_LOGITS + (size_t)EN*HEADS;
constexpr size_t OFF_INT    = OFF_HG     + (size_t)NB*HID;
// int region (indexed in ints from OFF_INT)
constexpr size_t IOFF_DEG    = 0;
constexpr size_t IOFF_ROWOFF = IOFF_DEG    + NN;
constexpr size_t IOFF_CURSOR = IOFF_ROWOFF + NN + 1;
constexpr size_t IOFF_CSRSRC = IOFF_CURSOR + NN;
constexpr size_t IOFF_CSREID = IOFF_CSRSRC + NE;
constexpr size_t IOFF_CNT    = IOFF_CSREID + NE;

// ---------------- utility ----------------
__global__ __launch_bounds__(256) void k_zero(float* p, int n) {
  int i = blockIdx.x*256 + threadIdx.x;
  for (; i < n; i += gridDim.x*256) p[i] = 0.f;
}

// h = x @ node_W + node_b   (x: [NN,64], W: [64,256])
__global__ __launch_bounds__(256) void k_node_embed(const float* __restrict__ x,
    const float* __restrict__ W, const float* __restrict__ b, float* __restrict__ h) {
  __shared__ float xs[4][ND];
  int n0 = blockIdx.x * 4;
  int tid = threadIdx.x;
  { int r = tid >> 6, j = tid & 63; xs[r][j] = x[(size_t)(n0+r)*ND + j]; }
  __syncthreads();
  int c = tid;
  float a0 = b[c], a1 = b[c], a2 = b[c], a3 = b[c];
  #pragma unroll 8
  for (int j = 0; j < ND; ++j) {
    float w = W[(size_t)j*HID + c];
    a0 += xs[0][j]*w; a1 += xs[1][j]*w; a2 += xs[2][j]*w; a3 += xs[3][j]*w;
  }
  h[(size_t)(n0+0)*HID+c]=a0; h[(size_t)(n0+1)*HID+c]=a1;
  h[(size_t)(n0+2)*HID+c]=a2; h[(size_t)(n0+3)*HID+c]=a3;
}

// ea = edge_attr @ edge_W + edge_b  (attr:[NE,16], W:[16,16])
__global__ __launch_bounds__(256) void k_edge_embed(const float* __restrict__ attr,
    const float* __restrict__ W, const float* __restrict__ b, float* __restrict__ ea) {
  int i = blockIdx.x*256 + threadIdx.x;
  const int total = NE * ED;
  for (; i < total; i += gridDim.x*256) {
    int e = i >> 4, c = i & 15;
    const float* row = attr + (size_t)e*ED;
    float acc = b[c];
    #pragma unroll
    for (int j = 0; j < ED; ++j) acc += row[j] * W[j*ED + c];
    ea[i] = acc;
  }
}

__global__ __launch_bounds__(256) void k_deg(const int* __restrict__ dst, int* deg) {
  int i = blockIdx.x*256 + threadIdx.x;
  for (; i < NE; i += gridDim.x*256) atomicAdd(&deg[dst[i]], 1);
}

// batch is sorted: cnt[b] = upper_bound(b) - lower_bound(b). No atomics.
__global__ __launch_bounds__(64) void k_cnt_bs(const int* __restrict__ batch, int* __restrict__ cnt) {
  int b = threadIdx.x;
  if (b >= NB) return;
  int lo = 0, hi = NN;
  while (lo < hi) { int mid = (lo+hi) >> 1; if (batch[mid] <  b) lo = mid+1; else hi = mid; }
  int lb = lo;
  lo = 0; hi = NN;
  while (lo < hi) { int mid = (lo+hi) >> 1; if (batch[mid] <= b) lo = mid+1; else hi = mid; }
  cnt[b] = lo - lb;
}

// single-block scan of deg -> row_off (excl prefix) + cursor copy; row_off[NN]=E
__global__ __launch_bounds__(1024) void k_scan(const int* __restrict__ deg,
    int* __restrict__ row_off, int* __restrict__ cursor) {
  __shared__ int sm[1024];
  const int CHK = (NN + 1023) / 1024;   // 20
  int t = threadIdx.x;
  int base = t * CHK;
  int s = 0;
  for (int i = 0; i < CHK; ++i) { int idx = base+i; if (idx < NN) s += deg[idx]; }
  sm[t] = s; __syncthreads();
  for (int off = 1; off < 1024; off <<= 1) {
    int v = (t >= off) ? sm[t-off] : 0;
    __syncthreads();
    sm[t] += v;
    __syncthreads();
  }
  int run = (t == 0) ? 0 : sm[t-1];
  for (int i = 0; i < CHK; ++i) {
    int idx = base+i;
    if (idx < NN) { row_off[idx] = run; cursor[idx] = run; run += deg[idx]; }
  }
  if (t == 1023) row_off[NN] = sm[1023];
}

__global__ __launch_bounds__(256) void k_fill(const int* __restrict__ src, const int* __restrict__ dst,
    int* cursor, int* __restrict__ csr_src, int* __restrict__ csr_eid) {
  int e = blockIdx.x*256 + threadIdx.x;
  for (; e < NE; e += gridDim.x*256) {
    int pos = atomicAdd(&cursor[dst[e]], 1);
    csr_src[pos] = src[e];
    csr_eid[pos] = e;
  }
}

// loop_ea[n,c] = sum_{e: dst=n} ea[e,c] / max(deg,1)
__global__ __launch_bounds__(256) void k_loopea(const float* __restrict__ ea,
    const int* __restrict__ row_off, const int* __restrict__ csr_eid, float* __restrict__ loopea) {
  int i = blockIdx.x*256 + threadIdx.x;
  const int total = NN * ED;
  for (; i < total; i += gridDim.x*256) {
    int n = i >> 4, c = i & 15;
    int b0 = row_off[n], b1 = row_off[n+1];
    float s = 0.f;
    for (int k = b0; k < b1; ++k) s += ea[(size_t)csr_eid[k]*ED + c];
    int dg = b1 - b0;
    loopea[i] = s / (float)(dg > 1 ? dg : 1);
  }
}

// dual GEMM: C{0,1} = A @ B{0,1} + bias{0,1};  A:[M,256] B:[256,256]
// 128x128 tile, BK=32, 256 threads, 8x8 micro with split sub-tiles
// (rows {ty*4, 64+ty*4}, cols {tx*4, 64+tx*4}) -> all LDS reads conflict-free.
constexpr int BM = 128, BN = 128, BK = 32;
__global__ __launch_bounds__(256) void k_gemm_dual(const float* __restrict__ A,
    const float* __restrict__ B0, const float* __restrict__ B1,
    const float* __restrict__ bias0, const float* __restrict__ bias1,
    float* __restrict__ C0, float* __restrict__ C1, int M) {
  __shared__ float As[BK][BM+4];   // transposed A tile
  __shared__ float Bs[BK][BN];
  const float* B    = blockIdx.z ? B1 : B0;
  const float* bias = blockIdx.z ? bias1 : bias0;
  float* C          = blockIdx.z ? C1 : C0;
  int tid = threadIdx.x;
  int tx = tid & 15, ty = tid >> 4;
  int m0 = blockIdx.x * BM, n0 = blockIdx.y * BN;
  float acc[8][8] = {};
  for (int k0 = 0; k0 < HID; k0 += BK) {
    // stage A: 128 rows x 32 cols = 1024 float4, 4 per thread
    #pragma unroll
    for (int i = tid; i < BM*(BK/4); i += 256) {
      int m = i >> 3, k4 = (i & 7) << 2;
      int gm = m0 + m;
      float4 v = make_float4(0.f,0.f,0.f,0.f);
      if (gm < M) v = *(const float4*)(A + (size_t)gm*HID + k0 + k4);
      As[k4+0][m]=v.x; As[k4+1][m]=v.y; As[k4+2][m]=v.z; As[k4+3][m]=v.w;
    }
    // stage B: 32 rows x 128 cols = 1024 float4, 4 per thread
    #pragma unroll
    for (int i = tid; i < BK*(BN/4); i += 256) {
      int kk = i >> 5, n4 = (i & 31) << 2;
      *(float4*)&Bs[kk][n4] = *(const float4*)(B + (size_t)(k0+kk)*HID + n0 + n4);
    }
    __syncthreads();
    #pragma unroll 8
    for (int kk = 0; kk < BK; ++kk) {
      float4 a0 = *(const float4*)&As[kk][ty*4];
      float4 a1 = *(const float4*)&As[kk][64 + ty*4];
      float4 b0 = *(const float4*)&Bs[kk][tx*4];
      float4 b1 = *(const float4*)&Bs[kk][64 + tx*4];
      float av[8] = {a0.x,a0.y,a0.z,a0.w, a1.x,a1.y,a1.z,a1.w};
      float bv[8] = {b0.x,b0.y,b0.z,b0.w, b1.x,b1.y,b1.z,b1.w};
      #pragma unroll
      for (int r = 0; r < 8; ++r)
        #pragma unroll
        for (int c = 0; c < 8; ++c)
          acc[r][c] += av[r]*bv[c];
    }
    __syncthreads();
  }
  float4 bb0 = *(const float4*)(bias + n0 + tx*4);
  float4 bb1 = *(const float4*)(bias + n0 + 64 + tx*4);
  #pragma unroll
  for (int r = 0; r < 8; ++r) {
    int gm = m0 + ((r < 4) ? (ty*4 + r) : (64 + ty*4 + (r-4)));
    if (gm < M) {
      float4 o0 = make_float4(acc[r][0]+bb0.x, acc[r][1]+bb0.y, acc[r][2]+bb0.z, acc[r][3]+bb0.w);
      float4 o1 = make_float4(acc[r][4]+bb1.x, acc[r][5]+bb1.y, acc[r][6]+bb1.z, acc[r][7]+bb1.w);
      *(float4*)(C + (size_t)gm*HID + n0 + tx*4)      = o0;
      *(float4*)(C + (size_t)gm*HID + n0 + 64 + tx*4) = o1;
    }
  }
}

// per-edge (incl self-loops) attention logits; one wave per edge
__global__ __launch_bounds__(256) void k_edge_logits(const float* __restrict__ xl,
    const float* __restrict__ xr, const float* __restrict__ ea, const float* __restrict__ loopea,
    const int* __restrict__ src, const int* __restrict__ dst,
    const float* __restrict__ We, const float* __restrict__ att, float* __restrict__ logits) {
  int lane = threadIdx.x & 63;
  int wid  = (blockIdx.x*256 + threadIdx.x) >> 6;
  int nw   = gridDim.x * 4;
  int c4   = lane * 4;
  int hh   = lane >> 3;
  float4 wv[16];
  #pragma unroll
  for (int j = 0; j < 16; ++j) wv[j] = *(const float4*)(We + (size_t)j*HID + c4);
  float at0 = att[hh*CH + (lane&7)*4 + 0];
  float at1 = att[hh*CH + (lane&7)*4 + 1];
  float at2 = att[hh*CH + (lane&7)*4 + 2];
  float at3 = att[hh*CH + (lane&7)*4 + 3];
  for (int e = wid; e < EN; e += nw) {
    int s, d; const float* eap;
    if (e < NE) { s = src[e]; d = dst[e]; eap = ea + (size_t)e*ED; }
    else        { s = e - NE; d = s;      eap = loopea + (size_t)s*ED; }
    float eav = (lane < 16) ? eap[lane] : 0.f;
    float4 acc = make_float4(0.f,0.f,0.f,0.f);
    #pragma unroll
    for (int j = 0; j < 16; ++j) {
      float ej = __shfl(eav, j);
      acc.x += ej*wv[j].x; acc.y += ej*wv[j].y; acc.z += ej*wv[j].z; acc.w += ej*wv[j].w;
    }
    float4 l4 = *(const float4*)(xl + (size_t)s*HID + c4);
    float4 r4 = *(const float4*)(xr + (size_t)d*HID + c4);
    float z0 = l4.x + r4.x + acc.x;
    float z1 = l4.y + r4.y + acc.y;
    float z2 = l4.z + r4.z + acc.z;
    float z3 = l4.w + r4.w + acc.w;
    z0 = z0 > 0.f ? z0 : z0*NEG_SLOPE;
    z1 = z1 > 0.f ? z1 : z1*NEG_SLOPE;
    z2 = z2 > 0.f ? z2 : z2*NEG_SLOPE;
    z3 = z3 > 0.f ? z3 : z3*NEG_SLOPE;
    float p = at0*z0 + at1*z1 + at2*z2 + at3*z3;
    p += __shfl_xor(p, 1);
    p += __shfl_xor(p, 2);
    p += __shfl_xor(p, 4);
    if ((lane & 7) == 0) logits[(size_t)e*HEADS + hh] = p;
  }
}

// per-node segment softmax + alpha-weighted aggregation + residual + bias; one wave per node
__global__ __launch_bounds__(256) void k_node_agg(const float* __restrict__ xl,
    const float* __restrict__ logits, const int* __restrict__ row_off,
    const int* __restrict__ csr_src, const int* __restrict__ csr_eid,
    const float* __restrict__ bias, float* __restrict__ h) {
  int lane = threadIdx.x & 63;
  int wid  = (blockIdx.x*256 + threadIdx.x) >> 6;
  int nw   = gridDim.x * 4;
  int c4   = lane * 4;
  int hh   = lane >> 3;
  for (int n = wid; n < NN; n += nw) {
    int b0 = row_off[n], b1 = row_off[n+1];
    float selfl = logits[(size_t)(NE+n)*HEADS + hh];
    float m = selfl;
    for (int k = b0; k < b1; ++k) m = fmaxf(m, logits[(size_t)csr_eid[k]*HEADS + hh]);
    float denom = expf(selfl - m);
    for (int k = b0; k < b1; ++k) denom += expf(logits[(size_t)csr_eid[k]*HEADS + hh] - m);
    float inv = 1.f / denom;
    float4 acc;
    {
      float w = expf(selfl - m) * inv;
      float4 v = *(const float4*)(xl + (size_t)n*HID + c4);
      acc = make_float4(w*v.x, w*v.y, w*v.z, w*v.w);
    }
    for (int k = b0; k < b1; ++k) {
      float w = expf(logits[(size_t)csr_eid[k]*HEADS + hh] - m) * inv;
      float4 v = *(const float4*)(xl + (size_t)csr_src[k]*HID + c4);
      acc.x += w*v.x; acc.y += w*v.y; acc.z += w*v.z; acc.w += w*v.w;
    }
    float4 hv = *(const float4*)(h + (size_t)n*HID + c4);
    float4 b4 = *(const float4*)(bias + c4);
    float4 o = make_float4(hv.x+acc.x+b4.x, hv.y+acc.y+b4.y, hv.z+acc.z+b4.z, hv.w+acc.w+b4.w);
    *(float4*)(h + (size_t)n*HID + c4) = o;
  }
}

// mean-pool numerator: run-accumulated atomics (batch is sorted)
__global__ __launch_bounds__(256) void k_pool(const float* __restrict__ h,
    const int* __restrict__ batch, float* __restrict__ hg) {
  int c = threadIdx.x;
  int per = (NN + gridDim.x - 1) / gridDim.x;
  int n0 = blockIdx.x * per, n1 = min(NN, n0 + per);
  if (n0 >= n1) return;
  int cur = batch[n0];
  float acc = 0.f;
  for (int n = n0; n < n1; ++n) {
    int b = batch[n];
    if (b != cur) { atomicAdd(&hg[(size_t)cur*HID + c], acc); acc = 0.f; cur = b; }
    acc += h[(size_t)n*HID + c];
  }
  atomicAdd(&hg[(size_t)cur*HID + c], acc);
}

// out = gelu(hg/cnt @ W1 + b1) @ W2 + b2 ; one block per graph
__global__ __launch_bounds__(256) void k_mlp(const float* __restrict__ hg, const int* __restrict__ cnt,
    const float* __restrict__ W1, const float* __restrict__ b1,
    const float* __restrict__ W2, const float* __restrict__ b2, float* __restrict__ out) {
  __shared__ float row[HID];
  __shared__ float zrow[HID];
  int b = blockIdx.x, c = threadIdx.x;
  float cn = (float)cnt[b]; cn = cn < 1.f ? 1.f : cn;
  row[c] = hg[(size_t)b*HID + c] / cn;
  __syncthreads();
  float acc = b1[c];
  for (int j = 0; j < HID; ++j) acc += row[j] * W1[(size_t)j*HID + c];
  float g = 0.5f * acc * (1.f + erff(acc * 0.70710678118654752440f));
  zrow[c] = g;
  __syncthreads();
  float acc2 = b2[c];
  for (int j = 0; j < HID; ++j) acc2 += zrow[j] * W2[(size_t)j*HID + c];
  out[(size_t)b*HID + c] = acc2;
}

extern "C" void kernel_launch(void* const* d_in, const int* in_sizes, int n_in,
                              void* d_out, int out_size, void* d_ws, size_t ws_size,
                              hipStream_t stream) {
  const float* x         = (const float*)d_in[0];
  const int*   edge_index= (const int*)  d_in[1];
  const float* edge_attr = (const float*)d_in[2];
  const int*   batch     = (const int*)  d_in[3];
  const float* node_W    = (const float*)d_in[4];
  const float* node_b    = (const float*)d_in[5];
  const float* edge_W    = (const float*)d_in[6];
  const float* edge_b    = (const float*)d_in[7];
  const float* Wl        = (const float*)d_in[8];
  const float* bl        = (const float*)d_in[9];
  const float* Wr        = (const float*)d_in[10];
  const float* br        = (const float*)d_in[11];
  const float* We        = (const float*)d_in[12];
  const float* att       = (const float*)d_in[13];
  const float* conv_bias = (const float*)d_in[14];
  const float* W1        = (const float*)d_in[15];
  const float* b1        = (const float*)d_in[16];
  const float* W2        = (const float*)d_in[17];
  const float* b2        = (const float*)d_in[18];
  const int* srcp = edge_index;
  const int* dstp = edge_index + NE;

  float* ws = (float*)d_ws;
  float* h      = ws + OFF_H;
  float* xl     = ws + OFF_XL;
  float* xr     = ws + OFF_XR;
  float* ea     = ws + OFF_EA;
  float* loopea = ws + OFF_LOOPEA;
  float* logits = ws + OFF_LOGITS;
  float* hg     = ws + OFF_HG;
  int* ib       = (int*)(ws + OFF_INT);
  int* deg      = ib + IOFF_DEG;
  int* row_off  = ib + IOFF_ROWOFF;
  int* cursor   = ib + IOFF_CURSOR;
  int* csr_src  = ib + IOFF_CSRSRC;
  int* csr_eid  = ib + IOFF_CSREID;
  int* cnt      = ib + IOFF_CNT;

  // zero accumulators (must happen every launch; harness doesn't re-poison)
  k_zero<<<8, 256, 0, stream>>>(hg, NB*HID);
  k_zero<<<80, 256, 0, stream>>>((float*)deg, NN);

  k_node_embed<<<NN/4, 256, 0, stream>>>(x, node_W, node_b, h);
  k_edge_embed<<<2048, 256, 0, stream>>>(edge_attr, edge_W, edge_b, ea);
  k_deg<<<1250, 256, 0, stream>>>(dstp, deg);
  k_cnt_bs<<<1, 64, 0, stream>>>(batch, cnt);
  k_scan<<<1, 1024, 0, stream>>>(deg, row_off, cursor);
  k_fill<<<1250, 256, 0, stream>>>(srcp, dstp, cursor, csr_src, csr_eid);
  k_loopea<<<1250, 256, 0, stream>>>(ea, row_off, csr_eid, loopea);

  for (int l = 0; l < NL; ++l) {
    dim3 g((NN + BM - 1)/BM, HID/BN, 2);
    k_gemm_dual<<<g, 256, 0, stream>>>(h,
        Wl + (size_t)l*HID*HID, Wr + (size_t)l*HID*HID,
        bl + (size_t)l*HID,     br + (size_t)l*HID,
        xl, xr, NN);
    k_edge_logits<<<2560, 256, 0, stream>>>(xl, xr, ea, loopea, srcp, dstp,
        We + (size_t)l*ED*HID, att + (size_t)l*HEADS*CH, logits);
    k_node_agg<<<1280, 256, 0, stream>>>(xl, logits, row_off, csr_src, csr_eid,
        conv_bias + (size_t)l*HID, h);
  }

  k_pool<<<80, 256, 0, stream>>>(h, batch, hg);
  k_mlp<<<NB, 256, 0, stream>>>(hg, cnt, W1, b1, W2, b2, (float*)d_out);
}

// Round 3
// 783.564 us; speedup vs baseline: 1.7807x; 1.5270x over previous
//
#include <hip/hip_runtime.h>
#include <math.h>

// ---------------- problem constants ----------------
constexpr int NN   = 20000;          // nodes
constexpr int NE   = 320000;         // edges
constexpr int ND   = 64;             // node dim
constexpr int ED   = 16;             // edge dim
constexpr int HID  = 256;
constexpr int HEADS= 8;
constexpr int CH   = 32;             // channels per head
constexpr int NB   = 16;             // graphs
constexpr int NL   = 3;              // layers
constexpr float NEG_SLOPE = 0.2f;

// ---------------- workspace layout (float units) ----------------
constexpr size_t OFF_H      = 0;
constexpr size_t OFF_XL     = OFF_H      + (size_t)NN*HID;
constexpr size_t OFF_XR     = OFF_XL     + (size_t)NN*HID;
constexpr size_t OFF_EA     = OFF_XR     + (size_t)NN*HID;
constexpr size_t OFF_LOOPEA = OFF_EA     + (size_t)NE*ED;
constexpr size_t OFF_HG     = OFF_LOOPEA + (size_t)NN*ED;
constexpr size_t OFF_INT    = OFF_HG     + (size_t)NB*HID;
// int region (indexed in ints from OFF_INT)
constexpr size_t IOFF_DEG    = 0;
constexpr size_t IOFF_ROWOFF = IOFF_DEG    + NN;
constexpr size_t IOFF_CURSOR = IOFF_ROWOFF + NN + 1;
constexpr size_t IOFF_CSRSRC = IOFF_CURSOR + NN;
constexpr size_t IOFF_CSREID = IOFF_CSRSRC + NE;
constexpr size_t IOFF_CNT    = IOFF_CSREID + NE;

// ---------------- utility ----------------
__global__ __launch_bounds__(256) void k_zero(float* p, int n) {
  int i = blockIdx.x*256 + threadIdx.x;
  for (; i < n; i += gridDim.x*256) p[i] = 0.f;
}

// h = x @ node_W + node_b   (x: [NN,64], W: [64,256])
__global__ __launch_bounds__(256) void k_node_embed(const float* __restrict__ x,
    const float* __restrict__ W, const float* __restrict__ b, float* __restrict__ h) {
  __shared__ float xs[4][ND];
  int n0 = blockIdx.x * 4;
  int tid = threadIdx.x;
  { int r = tid >> 6, j = tid & 63; xs[r][j] = x[(size_t)(n0+r)*ND + j]; }
  __syncthreads();
  int c = tid;
  float a0 = b[c], a1 = b[c], a2 = b[c], a3 = b[c];
  #pragma unroll 8
  for (int j = 0; j < ND; ++j) {
    float w = W[(size_t)j*HID + c];
    a0 += xs[0][j]*w; a1 += xs[1][j]*w; a2 += xs[2][j]*w; a3 += xs[3][j]*w;
  }
  h[(size_t)(n0+0)*HID+c]=a0; h[(size_t)(n0+1)*HID+c]=a1;
  h[(size_t)(n0+2)*HID+c]=a2; h[(size_t)(n0+3)*HID+c]=a3;
}

// ea = edge_attr @ edge_W + edge_b  (attr:[NE,16], W:[16,16])
__global__ __launch_bounds__(256) void k_edge_embed(const float* __restrict__ attr,
    const float* __restrict__ W, const float* __restrict__ b, float* __restrict__ ea) {
  int i = blockIdx.x*256 + threadIdx.x;
  const int total = NE * ED;
  for (; i < total; i += gridDim.x*256) {
    int e = i >> 4, c = i & 15;
    const float* row = attr + (size_t)e*ED;
    float acc = b[c];
    #pragma unroll
    for (int j = 0; j < ED; ++j) acc += row[j] * W[j*ED + c];
    ea[i] = acc;
  }
}

__global__ __launch_bounds__(256) void k_deg(const int* __restrict__ dst, int* deg) {
  int i = blockIdx.x*256 + threadIdx.x;
  for (; i < NE; i += gridDim.x*256) atomicAdd(&deg[dst[i]], 1);
}

// batch is sorted: cnt[b] = upper_bound(b) - lower_bound(b). No atomics.
__global__ __launch_bounds__(64) void k_cnt_bs(const int* __restrict__ batch, int* __restrict__ cnt) {
  int b = threadIdx.x;
  if (b >= NB) return;
  int lo = 0, hi = NN;
  while (lo < hi) { int mid = (lo+hi) >> 1; if (batch[mid] <  b) lo = mid+1; else hi = mid; }
  int lb = lo;
  lo = 0; hi = NN;
  while (lo < hi) { int mid = (lo+hi) >> 1; if (batch[mid] <= b) lo = mid+1; else hi = mid; }
  cnt[b] = lo - lb;
}

// single-block scan of deg -> row_off (excl prefix) + cursor copy; row_off[NN]=E
__global__ __launch_bounds__(1024) void k_scan(const int* __restrict__ deg,
    int* __restrict__ row_off, int* __restrict__ cursor) {
  __shared__ int sm[1024];
  const int CHK = (NN + 1023) / 1024;   // 20
  int t = threadIdx.x;
  int base = t * CHK;
  int s = 0;
  for (int i = 0; i < CHK; ++i) { int idx = base+i; if (idx < NN) s += deg[idx]; }
  sm[t] = s; __syncthreads();
  for (int off = 1; off < 1024; off <<= 1) {
    int v = (t >= off) ? sm[t-off] : 0;
    __syncthreads();
    sm[t] += v;
    __syncthreads();
  }
  int run = (t == 0) ? 0 : sm[t-1];
  for (int i = 0; i < CHK; ++i) {
    int idx = base+i;
    if (idx < NN) { row_off[idx] = run; cursor[idx] = run; run += deg[idx]; }
  }
  if (t == 1023) row_off[NN] = sm[1023];
}

__global__ __launch_bounds__(256) void k_fill(const int* __restrict__ src, const int* __restrict__ dst,
    int* cursor, int* __restrict__ csr_src, int* __restrict__ csr_eid) {
  int e = blockIdx.x*256 + threadIdx.x;
  for (; e < NE; e += gridDim.x*256) {
    int pos = atomicAdd(&cursor[dst[e]], 1);
    csr_src[pos] = src[e];
    csr_eid[pos] = e;
  }
}

// loop_ea[n,c] = sum_{e: dst=n} ea[e,c] / max(deg,1)
__global__ __launch_bounds__(256) void k_loopea(const float* __restrict__ ea,
    const int* __restrict__ row_off, const int* __restrict__ csr_eid, float* __restrict__ loopea) {
  int i = blockIdx.x*256 + threadIdx.x;
  const int total = NN * ED;
  for (; i < total; i += gridDim.x*256) {
    int n = i >> 4, c = i & 15;
    int b0 = row_off[n], b1 = row_off[n+1];
    float s = 0.f;
    for (int k = b0; k < b1; ++k) s += ea[(size_t)csr_eid[k]*ED + c];
    int dg = b1 - b0;
    loopea[i] = s / (float)(dg > 1 ? dg : 1);
  }
}

// dual GEMM: C{0,1} = A @ B{0,1} + bias{0,1};  A:[M,256] B:[256,256]
constexpr int BM = 128, BN = 128, BK = 32;
__global__ __launch_bounds__(256) void k_gemm_dual(const float* __restrict__ A,
    const float* __restrict__ B0, const float* __restrict__ B1,
    const float* __restrict__ bias0, const float* __restrict__ bias1,
    float* __restrict__ C0, float* __restrict__ C1, int M) {
  __shared__ float As[BK][BM+4];   // transposed A tile
  __shared__ float Bs[BK][BN];
  const float* B    = blockIdx.z ? B1 : B0;
  const float* bias = blockIdx.z ? bias1 : bias0;
  float* C          = blockIdx.z ? C1 : C0;
  int tid = threadIdx.x;
  int tx = tid & 15, ty = tid >> 4;
  int m0 = blockIdx.x * BM, n0 = blockIdx.y * BN;
  float acc[8][8] = {};
  for (int k0 = 0; k0 < HID; k0 += BK) {
    #pragma unroll
    for (int i = tid; i < BM*(BK/4); i += 256) {
      int m = i >> 3, k4 = (i & 7) << 2;
      int gm = m0 + m;
      float4 v = make_float4(0.f,0.f,0.f,0.f);
      if (gm < M) v = *(const float4*)(A + (size_t)gm*HID + k0 + k4);
      As[k4+0][m]=v.x; As[k4+1][m]=v.y; As[k4+2][m]=v.z; As[k4+3][m]=v.w;
    }
    #pragma unroll
    for (int i = tid; i < BK*(BN/4); i += 256) {
      int kk = i >> 5, n4 = (i & 31) << 2;
      *(float4*)&Bs[kk][n4] = *(const float4*)(B + (size_t)(k0+kk)*HID + n0 + n4);
    }
    __syncthreads();
    #pragma unroll 8
    for (int kk = 0; kk < BK; ++kk) {
      float4 a0 = *(const float4*)&As[kk][ty*4];
      float4 a1 = *(const float4*)&As[kk][64 + ty*4];
      float4 b0 = *(const float4*)&Bs[kk][tx*4];
      float4 b1 = *(const float4*)&Bs[kk][64 + tx*4];
      float av[8] = {a0.x,a0.y,a0.z,a0.w, a1.x,a1.y,a1.z,a1.w};
      float bv[8] = {b0.x,b0.y,b0.z,b0.w, b1.x,b1.y,b1.z,b1.w};
      #pragma unroll
      for (int r = 0; r < 8; ++r)
        #pragma unroll
        for (int c = 0; c < 8; ++c)
          acc[r][c] += av[r]*bv[c];
    }
    __syncthreads();
  }
  float4 bb0 = *(const float4*)(bias + n0 + tx*4);
  float4 bb1 = *(const float4*)(bias + n0 + 64 + tx*4);
  #pragma unroll
  for (int r = 0; r < 8; ++r) {
    int gm = m0 + ((r < 4) ? (ty*4 + r) : (64 + ty*4 + (r-4)));
    if (gm < M) {
      float4 o0 = make_float4(acc[r][0]+bb0.x, acc[r][1]+bb0.y, acc[r][2]+bb0.z, acc[r][3]+bb0.w);
      float4 o1 = make_float4(acc[r][4]+bb1.x, acc[r][5]+bb1.y, acc[r][6]+bb1.z, acc[r][7]+bb1.w);
      *(float4*)(C + (size_t)gm*HID + n0 + tx*4)      = o0;
      *(float4*)(C + (size_t)gm*HID + n0 + 64 + tx*4) = o1;
    }
  }
}

// ---- fused GATv2 attention: online softmax + aggregation, one wave per dst node ----
__device__ __forceinline__ float4 eemb16(const float4* __restrict__ w,
    float4 a, float4 b, float4 c, float4 d) {
  float e[16] = {a.x,a.y,a.z,a.w, b.x,b.y,b.z,b.w, c.x,c.y,c.z,c.w, d.x,d.y,d.z,d.w};
  float4 r = make_float4(0.f,0.f,0.f,0.f);
  #pragma unroll
  for (int j = 0; j < 16; ++j) {
    r.x += e[j]*w[j].x; r.y += e[j]*w[j].y; r.z += e[j]*w[j].z; r.w += e[j]*w[j].w;
  }
  return r;
}

__device__ __forceinline__ float head_logit(float4 z, float4 av) {
  // leaky relu then per-head (8-lane group) dot with att
  float z0 = z.x > 0.f ? z.x : z.x*NEG_SLOPE;
  float z1 = z.y > 0.f ? z.y : z.y*NEG_SLOPE;
  float z2 = z.z > 0.f ? z.z : z.z*NEG_SLOPE;
  float z3 = z.w > 0.f ? z.w : z.w*NEG_SLOPE;
  float p = z0*av.x + z1*av.y + z2*av.z + z3*av.w;
  p += __shfl_xor(p, 1);
  p += __shfl_xor(p, 2);
  p += __shfl_xor(p, 4);
  return p;
}

__global__ __launch_bounds__(256) void k_gat_fused(
    const float* __restrict__ xl, const float* __restrict__ xr,
    const float* __restrict__ ea, const float* __restrict__ loopea,
    const int* __restrict__ row_off, const int* __restrict__ csr_src,
    const int* __restrict__ csr_eid,
    const float* __restrict__ We, const float* __restrict__ att,
    const float* __restrict__ bias, float* __restrict__ h) {
  int lane = threadIdx.x & 63;
  int n = (blockIdx.x*256 + threadIdx.x) >> 6;
  if (n >= NN) return;
  int c4 = lane*4;
  int hh = lane >> 3;
  float4 wv[16];
  #pragma unroll
  for (int j = 0; j < 16; ++j) wv[j] = *(const float4*)(We + (size_t)j*HID + c4);
  float4 av  = *(const float4*)(att + hh*CH + (lane&7)*4);
  float4 xr4 = *(const float4*)(xr + (size_t)n*HID + c4);
  float4 xls = *(const float4*)(xl + (size_t)n*HID + c4);

  // self-loop initializes the online softmax state
  float m, denom; float4 acc;
  {
    const float* lp = loopea + (size_t)n*ED;
    float4 l0 = *(const float4*)(lp+0), l1 = *(const float4*)(lp+4);
    float4 l2 = *(const float4*)(lp+8), l3 = *(const float4*)(lp+12);
    float4 em = eemb16(wv, l0, l1, l2, l3);
    float4 z = make_float4(xls.x+xr4.x+em.x, xls.y+xr4.y+em.y,
                           xls.z+xr4.z+em.z, xls.w+xr4.w+em.w);
    m = head_logit(z, av);
    denom = 1.f;
    acc = xls;
  }

  int b0 = row_off[n], b1 = row_off[n+1];
  for (int kb = b0; kb < b1; kb += 64) {
    int nk = min(64, b1 - kb);
    int si = 0, ei = 0;
    if (lane < nk) { si = csr_src[kb+lane]; ei = csr_eid[kb+lane]; }
    // software pipeline: issue edge-0 loads
    int s0 = __shfl(si, 0), g0 = __shfl(ei, 0);
    float4 xn = *(const float4*)(xl + (size_t)s0*HID + c4);
    const float* ep = ea + (size_t)g0*ED;
    float4 a0 = *(const float4*)(ep+0), a1 = *(const float4*)(ep+4);
    float4 a2 = *(const float4*)(ep+8), a3 = *(const float4*)(ep+12);
    for (int t = 0; t < nk; ++t) {
      float4 xc = xn, c0 = a0, c1 = a1, c2 = a2, c3 = a3;
      if (t+1 < nk) {
        int s2 = __shfl(si, t+1), g2 = __shfl(ei, t+1);
        xn = *(const float4*)(xl + (size_t)s2*HID + c4);
        const float* ep2 = ea + (size_t)g2*ED;
        a0 = *(const float4*)(ep2+0); a1 = *(const float4*)(ep2+4);
        a2 = *(const float4*)(ep2+8); a3 = *(const float4*)(ep2+12);
      }
      float4 em = eemb16(wv, c0, c1, c2, c3);
      float4 z = make_float4(xc.x+xr4.x+em.x, xc.y+xr4.y+em.y,
                             xc.z+xr4.z+em.z, xc.w+xr4.w+em.w);
      float p = head_logit(z, av);
      float nm = fmaxf(m, p);
      float so = __expf(m - nm);
      float sn = __expf(p - nm);
      denom = denom*so + sn;
      acc.x = acc.x*so + sn*xc.x;
      acc.y = acc.y*so + sn*xc.y;
      acc.z = acc.z*so + sn*xc.z;
      acc.w = acc.w*so + sn*xc.w;
      m = nm;
    }
  }
  float inv = 1.f / denom;
  float* hp = h + (size_t)n*HID + c4;
  float4 hv = *(const float4*)hp;
  float4 b4 = *(const float4*)(bias + c4);
  hv.x += acc.x*inv + b4.x;
  hv.y += acc.y*inv + b4.y;
  hv.z += acc.z*inv + b4.z;
  hv.w += acc.w*inv + b4.w;
  *(float4*)hp = hv;
}

// mean-pool numerator: run-accumulated atomics (batch is sorted)
__global__ __launch_bounds__(256) void k_pool(const float* __restrict__ h,
    const int* __restrict__ batch, float* __restrict__ hg) {
  int c = threadIdx.x;
  int per = (NN + gridDim.x - 1) / gridDim.x;
  int n0 = blockIdx.x * per, n1 = min(NN, n0 + per);
  if (n0 >= n1) return;
  int cur = batch[n0];
  float acc = 0.f;
  for (int n = n0; n < n1; ++n) {
    int b = batch[n];
    if (b != cur) { atomicAdd(&hg[(size_t)cur*HID + c], acc); acc = 0.f; cur = b; }
    acc += h[(size_t)n*HID + c];
  }
  atomicAdd(&hg[(size_t)cur*HID + c], acc);
}

// out = gelu(hg/cnt @ W1 + b1) @ W2 + b2 ; one block per graph
__global__ __launch_bounds__(256) void k_mlp(const float* __restrict__ hg, const int* __restrict__ cnt,
    const float* __restrict__ W1, const float* __restrict__ b1,
    const float* __restrict__ W2, const float* __restrict__ b2, float* __restrict__ out) {
  __shared__ float row[HID];
  __shared__ float zrow[HID];
  int b = blockIdx.x, c = threadIdx.x;
  float cn = (float)cnt[b]; cn = cn < 1.f ? 1.f : cn;
  row[c] = hg[(size_t)b*HID + c] / cn;
  __syncthreads();
  float acc = b1[c];
  for (int j = 0; j < HID; ++j) acc += row[j] * W1[(size_t)j*HID + c];
  float g = 0.5f * acc * (1.f + erff(acc * 0.70710678118654752440f));
  zrow[c] = g;
  __syncthreads();
  float acc2 = b2[c];
  for (int j = 0; j < HID; ++j) acc2 += zrow[j] * W2[(size_t)j*HID + c];
  out[(size_t)b*HID + c] = acc2;
}

extern "C" void kernel_launch(void* const* d_in, const int* in_sizes, int n_in,
                              void* d_out, int out_size, void* d_ws, size_t ws_size,
                              hipStream_t stream) {
  const float* x         = (const float*)d_in[0];
  const int*   edge_index= (const int*)  d_in[1];
  const float* edge_attr = (const float*)d_in[2];
  const int*   batch     = (const int*)  d_in[3];
  const float* node_W    = (const float*)d_in[4];
  const float* node_b    = (const float*)d_in[5];
  const float* edge_W    = (const float*)d_in[6];
  const float* edge_b    = (const float*)d_in[7];
  const float* Wl        = (const float*)d_in[8];
  const float* bl        = (const float*)d_in[9];
  const float* Wr        = (const float*)d_in[10];
  const float* br        = (const float*)d_in[11];
  const float* We        = (const float*)d_in[12];
  const float* att       = (const float*)d_in[13];
  const float* conv_bias = (const float*)d_in[14];
  const float* W1        = (const float*)d_in[15];
  const float* b1        = (const float*)d_in[16];
  const float* W2        = (const float*)d_in[17];
  const float* b2        = (const float*)d_in[18];
  const int* srcp = edge_index;
  const int* dstp = edge_index + NE;

  float* ws = (float*)d_ws;
  float* h      = ws + OFF_H;
  float* xl     = ws + OFF_XL;
  float* xr     = ws + OFF_XR;
  float* ea     = ws + OFF_EA;
  float* loopea = ws + OFF_LOOPEA;
  float* hg     = ws + OFF_HG;
  int* ib       = (int*)(ws + OFF_INT);
  int* deg      = ib + IOFF_DEG;
  int* row_off  = ib + IOFF_ROWOFF;
  int* cursor   = ib + IOFF_CURSOR;
  int* csr_src  = ib + IOFF_CSRSRC;
  int* csr_eid  = ib + IOFF_CSREID;
  int* cnt      = ib + IOFF_CNT;

  // zero accumulators (must happen every launch; harness doesn't re-poison)
  k_zero<<<8, 256, 0, stream>>>(hg, NB*HID);
  k_zero<<<80, 256, 0, stream>>>((float*)deg, NN);

  k_node_embed<<<NN/4, 256, 0, stream>>>(x, node_W, node_b, h);
  k_edge_embed<<<2048, 256, 0, stream>>>(edge_attr, edge_W, edge_b, ea);
  k_deg<<<1250, 256, 0, stream>>>(dstp, deg);
  k_cnt_bs<<<1, 64, 0, stream>>>(batch, cnt);
  k_scan<<<1, 1024, 0, stream>>>(deg, row_off, cursor);
  k_fill<<<1250, 256, 0, stream>>>(srcp, dstp, cursor, csr_src, csr_eid);
  k_loopea<<<1250, 256, 0, stream>>>(ea, row_off, csr_eid, loopea);

  for (int l = 0; l < NL; ++l) {
    dim3 g((NN + BM - 1)/BM, HID/BN, 2);
    k_gemm_dual<<<g, 256, 0, stream>>>(h,
        Wl + (size_t)l*HID*HID, Wr + (size_t)l*HID*HID,
        bl + (size_t)l*HID,     br + (size_t)l*HID,
        xl, xr, NN);
    k_gat_fused<<<(NN*64 + 255)/256, 256, 0, stream>>>(xl, xr, ea, loopea,
        row_off, csr_src, csr_eid,
        We + (size_t)l*ED*HID, att + (size_t)l*HEADS*CH,
        conv_bias + (size_t)l*HID, h);
  }

  k_pool<<<80, 256, 0, stream>>>(h, batch, hg);
  k_mlp<<<NB, 256, 0, stream>>>(hg, cnt, W1, b1, W2, b2, (float*)d_out);
}